// Round 4
// baseline (10677.946 us; speedup 1.0000x reference)
//
#include <hip/hip_runtime.h>
#include <hip/hip_bf16.h>

#define BDIM 2
#define SDIM 4096
#define EDIM 2048
#define TOK (BDIM * SDIM)       // 8192
#define KVN (2 * EDIM)          // 4096
#define CHUNK 1024              // score-chunk rows
#define QK_SCALE 0.08838834764831845f  // 128^-0.5

// ---------- load/convert helpers ----------
__device__ __forceinline__ void load4f(const float* p, float f[4]) {
    const float4 v = *reinterpret_cast<const float4*>(p);
    f[0] = v.x; f[1] = v.y; f[2] = v.z; f[3] = v.w;
}
__device__ __forceinline__ void load4f(const __hip_bfloat16* p, float f[4]) {
    const ushort4 u = *reinterpret_cast<const ushort4*>(p);
    f[0] = __uint_as_float(((unsigned)u.x) << 16);
    f[1] = __uint_as_float(((unsigned)u.y) << 16);
    f[2] = __uint_as_float(((unsigned)u.z) << 16);
    f[3] = __uint_as_float(((unsigned)u.w) << 16);
}
__device__ __forceinline__ float tofl(float v) { return v; }
__device__ __forceinline__ float tofl(__hip_bfloat16 v) { return __bfloat162float(v); }
__device__ __forceinline__ void storec(float* p, float v) { *p = v; }
__device__ __forceinline__ void storec(__hip_bfloat16* p, float v) { *p = __float2bfloat16(v); }

// ---------- generic tiled GEMM ----------
// MODE 0: C[m,n] = sum_k A[m,k]*B[n,k]   (B is NxK row-major, i.e. A@B^T)
// MODE 1: C[m,n] = sum_k A[m,k]*B[k,n]   (B is KxN row-major)
// C = (acc + bias[n]) * scale.  64x64 tile, BK=16, 256 threads, 4x4 per thread.
template <typename TA, typename TB, typename TC, int MODE>
__global__ __launch_bounds__(256) void gemm_kernel(
    const TA* __restrict__ A, int lda,
    const TB* __restrict__ B, int ldb,
    TC* __restrict__ C, int ldc,
    const TB* __restrict__ bias, float scale, int K) {

    const int tid = threadIdx.x;
    const int tx = tid & 15;        // n dir
    const int ty = tid >> 4;        // m dir
    const int m0 = blockIdx.y * 64;
    const int n0 = blockIdx.x * 64;

    __shared__ float As[64][17];
    __shared__ float Bs[16][65];

    float c[4][4];
#pragma unroll
    for (int i = 0; i < 4; ++i)
#pragma unroll
        for (int j = 0; j < 4; ++j) c[i][j] = 0.0f;

    const int arow = tid >> 2;           // 0..63
    const int acol = (tid & 3) * 4;      // 0,4,8,12

    for (int kt = 0; kt < K; kt += 16) {
        {
            float v[4];
            load4f(A + (long)(m0 + arow) * lda + kt + acol, v);
#pragma unroll
            for (int j = 0; j < 4; ++j) As[arow][acol + j] = v[j];
        }
        if (MODE == 0) {
            float v[4];
            load4f(B + (long)(n0 + arow) * ldb + kt + acol, v);
#pragma unroll
            for (int j = 0; j < 4; ++j) Bs[acol + j][arow] = v[j];
        } else {
            const int krow = tid >> 4;        // 0..15
            const int ncol = (tid & 15) * 4;  // 0..60
            float v[4];
            load4f(B + (long)(kt + krow) * ldb + n0 + ncol, v);
#pragma unroll
            for (int j = 0; j < 4; ++j) Bs[krow][ncol + j] = v[j];
        }
        __syncthreads();

#pragma unroll
        for (int kk = 0; kk < 16; ++kk) {
            float a[4], b[4];
#pragma unroll
            for (int i = 0; i < 4; ++i) a[i] = As[ty * 4 + i][kk];
#pragma unroll
            for (int j = 0; j < 4; ++j) b[j] = Bs[kk][tx * 4 + j];
#pragma unroll
            for (int i = 0; i < 4; ++i)
#pragma unroll
                for (int j = 0; j < 4; ++j) c[i][j] += a[i] * b[j];
        }
        __syncthreads();
    }

    float bv[4];
#pragma unroll
    for (int j = 0; j < 4; ++j)
        bv[j] = bias ? tofl(bias[n0 + tx * 4 + j]) : 0.0f;

#pragma unroll
    for (int i = 0; i < 4; ++i) {
        const long row = m0 + ty * 4 + i;
#pragma unroll
        for (int j = 0; j < 4; ++j) {
            storec(C + row * ldc + n0 + tx * 4 + j, (c[i][j] + bv[j]) * scale);
        }
    }
}

// ---------- RoPE in-place on bf16 (TOK x ld), first 2048 cols = 16 heads x 128 ----------
__global__ __launch_bounds__(256) void rope_kernel(__hip_bfloat16* __restrict__ p, int ld) {
    const long idx = (long)blockIdx.x * 256 + threadIdx.x;  // < TOK*1024
    const int m = (int)(idx >> 10);
    const int r = (int)(idx & 1023);
    const int h = r >> 6;
    const int i = r & 63;
    const int s = m & (SDIM - 1);
    const float f = (float)s * expf(-(float)i * 0.14391156831212787f);
    float cs, sn;
    sincosf(f, &sn, &cs);
    __hip_bfloat16* b = p + (long)m * ld + h * 128 + i;
    const float x1 = __bfloat162float(b[0]);
    const float x2 = __bfloat162float(b[64]);
    b[0]  = __float2bfloat16(x1 * cs - x2 * sn);
    b[64] = __float2bfloat16(x2 * cs + x1 * sn);
}

// ---------- row softmax over 4096 (fp32, in place) ----------
__global__ __launch_bounds__(256) void softmax_kernel(float* __restrict__ S) {
    const long row = blockIdx.x;
    float* p = S + row * 4096;
    const int tid = threadIdx.x;
    const int lane = tid & 63;
    const int w = tid >> 6;
    __shared__ float red[4];

    float x[16];
#pragma unroll
    for (int i = 0; i < 4; ++i) {
        const float4 v = reinterpret_cast<const float4*>(p)[i * 256 + tid];
        x[i * 4 + 0] = v.x; x[i * 4 + 1] = v.y; x[i * 4 + 2] = v.z; x[i * 4 + 3] = v.w;
    }
    float m = -1e30f;
#pragma unroll
    for (int i = 0; i < 16; ++i) m = fmaxf(m, x[i]);
#pragma unroll
    for (int off = 1; off < 64; off <<= 1) m = fmaxf(m, __shfl_xor(m, off));
    if (lane == 0) red[w] = m;
    __syncthreads();
    const float M = fmaxf(fmaxf(red[0], red[1]), fmaxf(red[2], red[3]));
    __syncthreads();

    float s = 0.0f;
#pragma unroll
    for (int i = 0; i < 16; ++i) { x[i] = __expf(x[i] - M); s += x[i]; }
#pragma unroll
    for (int off = 1; off < 64; off <<= 1) s += __shfl_xor(s, off);
    if (lane == 0) red[w] = s;
    __syncthreads();
    const float inv = 1.0f / (red[0] + red[1] + red[2] + red[3]);

#pragma unroll
    for (int i = 0; i < 4; ++i) {
        float4 v;
        v.x = x[i * 4 + 0] * inv; v.y = x[i * 4 + 1] * inv;
        v.z = x[i * 4 + 2] * inv; v.w = x[i * 4 + 3] * inv;
        reinterpret_cast<float4*>(p)[i * 256 + tid] = v;
    }
}

extern "C" void kernel_launch(void* const* d_in, const int* in_sizes, int n_in,
                              void* d_out, int out_size, void* d_ws, size_t ws_size,
                              hipStream_t stream) {
    // Inputs fp32 (proven: fp32-as-bf16 NaN'd in R2). Output fp32 (reference
    // output dtype; R3's bf16 writes produced the shuffled-value absmax 5.79).
    const float* x    = (const float*)d_in[0];
    const float* q_w  = (const float*)d_in[1];
    const float* q_b  = (const float*)d_in[2];
    const float* kv_w = (const float*)d_in[3];
    const float* kv_b = (const float*)d_in[4];
    const float* o_w  = (const float*)d_in[5];
    float* out = (float*)d_out;

    // ws layout: QO bf16 [TOK x 2048] (32MB) | KV bf16 [TOK x 4096] (64MB)
    //            | Sc fp32 [CHUNK x 4096] (16MB).  Peak 112 MB (mapped OK in R2/R3).
    __hip_bfloat16* qo = (__hip_bfloat16*)d_ws;
    __hip_bfloat16* kv = qo + (long)TOK * EDIM;
    float* sc = (float*)(kv + (long)TOK * KVN);

    // 1) q = (x @ q_w^T + q_b) * scale   -> bf16
    gemm_kernel<float, float, __hip_bfloat16, 0>
        <<<dim3(EDIM / 64, TOK / 64), 256, 0, stream>>>(
            x, EDIM, q_w, EDIM, qo, EDIM, q_b, QK_SCALE, EDIM);

    // 2) kv = x @ kv_w^T + kv_b          -> bf16
    gemm_kernel<float, float, __hip_bfloat16, 0>
        <<<dim3(KVN / 64, TOK / 64), 256, 0, stream>>>(
            x, EDIM, kv_w, EDIM, kv, KVN, kv_b, 1.0f, EDIM);

    // 3) RoPE on q (all 2048 cols) and on k = kv[:, :2048]
    rope_kernel<<<(long)TOK * 1024 / 256, 256, 0, stream>>>(qo, EDIM);
    rope_kernel<<<(long)TOK * 1024 / 256, 256, 0, stream>>>(kv, KVN);

    // 4) chunked attention: Sc = q_chunk @ k_b^T ; softmax; o_chunk = Sc @ v_b
    for (int c = 0; c < TOK / CHUNK; ++c) {
        const long r0 = (long)c * CHUNK;
        const long b = r0 / SDIM;
        const __hip_bfloat16* kb = kv + b * (long)SDIM * KVN;          // k part
        const __hip_bfloat16* vb = kb + EDIM;                          // v part

        gemm_kernel<__hip_bfloat16, __hip_bfloat16, float, 0>
            <<<dim3(SDIM / 64, CHUNK / 64), 256, 0, stream>>>(
                qo + r0 * EDIM, EDIM, kb, KVN, sc, SDIM,
                (const __hip_bfloat16*)nullptr, 1.0f, EDIM);

        softmax_kernel<<<CHUNK, 256, 0, stream>>>(sc);

        gemm_kernel<float, __hip_bfloat16, __hip_bfloat16, 1>
            <<<dim3(EDIM / 64, CHUNK / 64), 256, 0, stream>>>(
                sc, SDIM, vb, KVN, (__hip_bfloat16*)(qo + r0 * EDIM), EDIM,
                (const __hip_bfloat16*)nullptr, 1.0f, SDIM);
    }

    // 5) out = o @ o_w^T  -> fp32
    gemm_kernel<__hip_bfloat16, float, float, 0>
        <<<dim3(EDIM / 64, TOK / 64), 256, 0, stream>>>(
            qo, EDIM, o_w, EDIM, out, EDIM,
            (const float*)nullptr, 1.0f, EDIM);
}

// Round 6
// 2055.552 us; speedup vs baseline: 5.1947x; 5.1947x over previous
//
#include <hip/hip_runtime.h>
#include <hip/hip_bf16.h>

#define BDIM 2
#define SDIM 4096
#define EDIM 2048
#define TOK (BDIM * SDIM)       // 8192
#define CHUNK 1024
#define QK_SCALE 0.08838834764831845f  // 128^-0.5

typedef short bf16x8 __attribute__((ext_vector_type(8)));
typedef float f32x4 __attribute__((ext_vector_type(4)));

__device__ __forceinline__ unsigned short f2bf(float f) {
    unsigned u = __float_as_uint(f);
    u += 0x7FFF + ((u >> 16) & 1);          // RNE; inputs finite
    return (unsigned short)(u >> 16);
}

// fp32x8 -> bf16 hi + bf16 lo (residual), for near-fp32 MFMA via 3-term split
__device__ __forceinline__ void cvt_split8(const float4 a, const float4 b,
                                           bf16x8& hi, bf16x8& lo) {
    float f[8] = {a.x, a.y, a.z, a.w, b.x, b.y, b.z, b.w};
#pragma unroll
    for (int i = 0; i < 8; ++i) {
        const unsigned short h = f2bf(f[i]);
        hi[i] = (short)h;
        const float hf = __uint_as_float(((unsigned)h) << 16);
        lo[i] = (short)f2bf(f[i] - hf);
    }
}

// async 16B global -> LDS (wave-uniform base + lane*16 layout; LDS unpadded)
__device__ __forceinline__ void cp16(const void* g, void* l) {
    __builtin_amdgcn_global_load_lds(
        (const __attribute__((address_space(1))) unsigned int*)g,
        (__attribute__((address_space(3))) unsigned int*)l, 16, 0, 0);
}

// ---------------- MFMA GEMM: C[m,n] = sum_k A[m,k] * B^T[n,k] ----------------
// A: M x K row-major, B: N x K row-major (B^T form). 128x128 tile, BK=32,
// 256 threads = 4 waves (2x2 of 64x64), mfma_f32_16x16x32_bf16.
// SA/SB: 0 = operand is bf16 in global (cp16 direct);
//        1 = operand is fp32 in global -> split into bf16 hi+lo tiles; the
//            product uses Ah*Bh + Ah*Bl + Al*Bh (near-fp32 precision).
// EPI: 0 = fp32 store to Cp;  1 = bf16 store to Cp;
//      2 = kv-split: n<2048 -> bf16 Cp (ldc), n>=2048 -> transposed bf16 Ct:
//          Ct[(batch*2048 + n-2048)*ldt + row_in_batch], batch = row>>12.
// C = (acc + bias[n]) * scale (bias fp32, nullable).
template <int SA, int SB, int EPI>
__global__ __launch_bounds__(256) void mfma_gemm(
    const void* __restrict__ Ap, int lda,
    const void* __restrict__ Bp, int ldb,
    void* __restrict__ Cp, int ldc,
    unsigned short* __restrict__ Ct, int ldt,
    const float* __restrict__ bias, float scale, int K) {

    __shared__ short As[(SA ? 2 : 1) * 128 * 32];   // [+4096]: lo tile
    __shared__ short Bs[(SB ? 2 : 1) * 128 * 32];

    const int tid = threadIdx.x;
    const int m0 = blockIdx.y * 128;
    const int n0 = blockIdx.x * 128;

    const int lane = tid & 63;
    const int wave = tid >> 6;
    const int ln = lane & 15;
    const int quad = lane >> 4;
    const int wm = (wave >> 1) * 64;
    const int wn = (wave & 1) * 64;

    f32x4 acc[4][4] = {};

    const int srow = tid >> 2;          // 0..63 (+64 second pass)
    const int scol = (tid & 3) * 8;     // 0,8,16,24

    for (int kt = 0; kt < K; kt += 32) {
        if (kt) __syncthreads();

        // ---- stage A tile (128x32 bf16 [+lo]) ----
        if (SA) {
#pragma unroll
            for (int p = 0; p < 2; ++p) {
                const int r = p * 64 + srow;
                const float* s = (const float*)Ap + (long)(m0 + r) * lda + kt + scol;
                const float4 f0 = *(const float4*)s;
                const float4 f1 = *(const float4*)(s + 4);
                bf16x8 hi, lo;
                cvt_split8(f0, f1, hi, lo);
                *(bf16x8*)&As[r * 32 + scol] = hi;
                *(bf16x8*)&As[4096 + r * 32 + scol] = lo;
            }
        } else {
#pragma unroll
            for (int p = 0; p < 2; ++p) {
                const int r = p * 64 + srow;
                cp16((const unsigned short*)Ap + (long)(m0 + r) * lda + kt + scol,
                     &As[r * 32 + scol]);
            }
        }
        // ---- stage B tile (128x32 bf16 [+lo], B^T rows) ----
        if (SB) {
#pragma unroll
            for (int p = 0; p < 2; ++p) {
                const int r = p * 64 + srow;
                const float* s = (const float*)Bp + (long)(n0 + r) * ldb + kt + scol;
                const float4 f0 = *(const float4*)s;
                const float4 f1 = *(const float4*)(s + 4);
                bf16x8 hi, lo;
                cvt_split8(f0, f1, hi, lo);
                *(bf16x8*)&Bs[r * 32 + scol] = hi;
                *(bf16x8*)&Bs[4096 + r * 32 + scol] = lo;
            }
        } else {
#pragma unroll
            for (int p = 0; p < 2; ++p) {
                const int r = p * 64 + srow;
                cp16((const unsigned short*)Bp + (long)(n0 + r) * ldb + kt + scol,
                     &Bs[r * 32 + scol]);
            }
        }
        __syncthreads();   // drains vmcnt (global_load_lds) + lgkm (ds_write)

        // ---- fragments + MFMA ----
        bf16x8 ah[4], bh[4];
#pragma unroll
        for (int t = 0; t < 4; ++t)
            ah[t] = *(bf16x8*)&As[(wm + t * 16 + ln) * 32 + quad * 8];
#pragma unroll
        for (int t = 0; t < 4; ++t)
            bh[t] = *(bf16x8*)&Bs[(wn + t * 16 + ln) * 32 + quad * 8];

#pragma unroll
        for (int i = 0; i < 4; ++i)
#pragma unroll
            for (int j = 0; j < 4; ++j)
                acc[i][j] = __builtin_amdgcn_mfma_f32_16x16x32_bf16(
                    ah[i], bh[j], acc[i][j], 0, 0, 0);

        if (SB) {
            bf16x8 bl[4];
#pragma unroll
            for (int t = 0; t < 4; ++t)
                bl[t] = *(bf16x8*)&Bs[4096 + (wn + t * 16 + ln) * 32 + quad * 8];
#pragma unroll
            for (int i = 0; i < 4; ++i)
#pragma unroll
                for (int j = 0; j < 4; ++j)
                    acc[i][j] = __builtin_amdgcn_mfma_f32_16x16x32_bf16(
                        ah[i], bl[j], acc[i][j], 0, 0, 0);
        }
        if (SA) {
            bf16x8 al[4];
#pragma unroll
            for (int t = 0; t < 4; ++t)
                al[t] = *(bf16x8*)&As[4096 + (wm + t * 16 + ln) * 32 + quad * 8];
#pragma unroll
            for (int i = 0; i < 4; ++i)
#pragma unroll
                for (int j = 0; j < 4; ++j)
                    acc[i][j] = __builtin_amdgcn_mfma_f32_16x16x32_bf16(
                        al[i], bh[j], acc[i][j], 0, 0, 0);
        }
    }

    // ---- epilogue: C/D layout col=lane&15, row=quad*4+reg ----
#pragma unroll
    for (int i = 0; i < 4; ++i) {
        const int gm = m0 + wm + i * 16 + quad * 4;      // rows gm..gm+3
#pragma unroll
        for (int j = 0; j < 4; ++j) {
            const int gn = n0 + wn + j * 16 + ln;
            const float bv = bias ? bias[gn] : 0.0f;
            const f32x4 d = acc[i][j];
            if (EPI == 2 && gn >= 2048) {
                const int bt = gm >> 12;
                const int rl = gm & 4095;
                ushort4 t4;
                t4.x = f2bf((d[0] + bv) * scale);
                t4.y = f2bf((d[1] + bv) * scale);
                t4.z = f2bf((d[2] + bv) * scale);
                t4.w = f2bf((d[3] + bv) * scale);
                *(ushort4*)&Ct[((long)bt * 2048 + (gn - 2048)) * ldt + rl] = t4;
            } else if (EPI == 0) {
                float* Cf = (float*)Cp;
#pragma unroll
                for (int r = 0; r < 4; ++r)
                    Cf[(long)(gm + r) * ldc + gn] = (d[r] + bv) * scale;
            } else {
                unsigned short* Cb = (unsigned short*)Cp;
#pragma unroll
                for (int r = 0; r < 4; ++r)
                    Cb[(long)(gm + r) * ldc + gn] = f2bf((d[r] + bv) * scale);
            }
        }
    }
}

// ---------- RoPE in-place on bf16 (TOK x ld), ld cols = 16 heads x 128 ----------
__global__ __launch_bounds__(256) void rope_kernel(__hip_bfloat16* __restrict__ p, int ld) {
    const long idx = (long)blockIdx.x * 256 + threadIdx.x;  // < TOK*1024
    const int m = (int)(idx >> 10);
    const int r = (int)(idx & 1023);
    const int h = r >> 6;
    const int i = r & 63;
    const int s = m & (SDIM - 1);
    const float f = (float)s * expf(-(float)i * 0.14391156831212787f);
    float cs, sn;
    sincosf(f, &sn, &cs);
    __hip_bfloat16* b = p + (long)m * ld + h * 128 + i;
    const float x1 = __bfloat162float(b[0]);
    const float x2 = __bfloat162float(b[64]);
    b[0]  = __float2bfloat16(x1 * cs - x2 * sn);
    b[64] = __float2bfloat16(x2 * cs + x1 * sn);
}

// ---------- row softmax over 4096: read fp32, write bf16 in place ----------
__global__ __launch_bounds__(256) void softmax_kernel(float* __restrict__ S) {
    const long row = blockIdx.x;
    float* p = S + row * 4096;
    const int tid = threadIdx.x;
    const int lane = tid & 63;
    const int w = tid >> 6;
    __shared__ float red[4];

    float x[16];
#pragma unroll
    for (int i = 0; i < 4; ++i) {
        const float4 v = reinterpret_cast<const float4*>(p)[i * 256 + tid];
        x[i * 4 + 0] = v.x; x[i * 4 + 1] = v.y; x[i * 4 + 2] = v.z; x[i * 4 + 3] = v.w;
    }
    float m = -1e30f;
#pragma unroll
    for (int i = 0; i < 16; ++i) m = fmaxf(m, x[i]);
#pragma unroll
    for (int off = 1; off < 64; off <<= 1) m = fmaxf(m, __shfl_xor(m, off));
    if (lane == 0) red[w] = m;
    __syncthreads();
    const float M = fmaxf(fmaxf(red[0], red[1]), fmaxf(red[2], red[3]));
    __syncthreads();

    float s = 0.0f;
#pragma unroll
    for (int i = 0; i < 16; ++i) { x[i] = __expf(x[i] - M); s += x[i]; }
#pragma unroll
    for (int off = 1; off < 64; off <<= 1) s += __shfl_xor(s, off);
    if (lane == 0) red[w] = s;
    __syncthreads();                 // all reads done before in-place bf16 write
    const float inv = 1.0f / (red[0] + red[1] + red[2] + red[3]);

    ushort4* dst = (ushort4*)p;      // bf16 packed into first half of the row
#pragma unroll
    for (int i = 0; i < 4; ++i) {
        ushort4 t;
        t.x = f2bf(x[i * 4 + 0] * inv); t.y = f2bf(x[i * 4 + 1] * inv);
        t.z = f2bf(x[i * 4 + 2] * inv); t.w = f2bf(x[i * 4 + 3] * inv);
        dst[i * 256 + tid] = t;
    }
}

extern "C" void kernel_launch(void* const* d_in, const int* in_sizes, int n_in,
                              void* d_out, int out_size, void* d_ws, size_t ws_size,
                              hipStream_t stream) {
    const float* x    = (const float*)d_in[0];
    const float* q_w  = (const float*)d_in[1];
    const float* q_b  = (const float*)d_in[2];
    const float* kv_w = (const float*)d_in[3];
    const float* kv_b = (const float*)d_in[4];
    const float* o_w  = (const float*)d_in[5];
    float* out = (float*)d_out;

    // ws (112 MiB total, proven mapped):
    //   qo bf16 [8192 x 2048] 32MB | K bf16 [8192 x 2048] 32MB
    // | VT bf16 [2 x 2048 x 4096] 32MB | sc fp32 [1024 x 4096] 16MB
    unsigned short* qo = (unsigned short*)d_ws;
    unsigned short* kb = qo + (long)TOK * EDIM;
    unsigned short* vT = kb + (long)TOK * EDIM;
    float* sc = (float*)(vT + (long)BDIM * EDIM * SDIM);

    // 1) q = (x @ q_w^T + q_b) * scale -> qo bf16   [split x, split q_w: ~fp32]
    mfma_gemm<1, 1, 1><<<dim3(EDIM / 128, TOK / 128), 256, 0, stream>>>(
        x, EDIM, q_w, EDIM, qo, EDIM, nullptr, 0, q_b, QK_SCALE, EDIM);

    // 2) kv = x @ kv_w^T + kv_b -> K bf16 + VT bf16 transposed   [split both]
    mfma_gemm<1, 1, 2><<<dim3(2 * EDIM / 128, TOK / 128), 256, 0, stream>>>(
        x, EDIM, kv_w, EDIM, kb, EDIM, vT, SDIM, kv_b, 1.0f, EDIM);

    // 3) RoPE on q and k
    rope_kernel<<<(long)TOK * 1024 / 256, 256, 0, stream>>>((__hip_bfloat16*)qo, EDIM);
    rope_kernel<<<(long)TOK * 1024 / 256, 256, 0, stream>>>((__hip_bfloat16*)kb, EDIM);

    // 4) chunked attention
    for (int c = 0; c < TOK / CHUNK; ++c) {
        const long r0 = (long)c * CHUNK;
        const long b = r0 >> 12;                       // batch index

        // scores = q_chunk @ k_b^T  (fp32 into sc)    [bf16 q,k — as R4]
        mfma_gemm<0, 0, 0><<<dim3(SDIM / 128, CHUNK / 128), 256, 0, stream>>>(
            qo + r0 * EDIM, EDIM, kb + b * SDIM * EDIM, EDIM,
            sc, SDIM, nullptr, 0, nullptr, 1.0f, EDIM);

        // softmax rows: fp32 -> bf16 in place
        softmax_kernel<<<CHUNK, 256, 0, stream>>>(sc);

        // o_chunk = P @ (VT)^T  (bf16 into qo rows)
        mfma_gemm<0, 0, 1><<<dim3(EDIM / 128, CHUNK / 128), 256, 0, stream>>>(
            (unsigned short*)sc, 2 * SDIM,             // P bf16, row stride 8192
            vT + b * (long)EDIM * SDIM, SDIM,
            qo + r0 * EDIM, EDIM, nullptr, 0, nullptr, 1.0f, SDIM);
    }

    // 5) out = o @ o_w^T -> fp32   [o bf16 direct, split o_w: matches R4]
    mfma_gemm<0, 1, 0><<<dim3(EDIM / 128, TOK / 128), 256, 0, stream>>>(
        qo, EDIM, o_w, EDIM, out, EDIM, nullptr, 0, nullptr, 1.0f, EDIM);
}